// Round 5
// baseline (369.083 us; speedup 1.0000x reference)
//
#include <hip/hip_runtime.h>

// Problem constants (fixed by the reference: B=16, D=256, K=64, H=W=96)
#define NDIM  256
#define NK    64
#define NPIX  9216
#define NB    16
#define TN    64           // pixels per tile
#define NW    48           // writer blocks per batch
#define TPB   3            // tiles per block = 144/NW
#define GRID  (NB*NW)      // 768 = exactly 3 blocks/CU resident -> one pass

typedef _Float16 half2_t __attribute__((ext_vector_type(2)));
typedef _Float16 half4_t __attribute__((ext_vector_type(4)));
typedef _Float16 half8_t __attribute__((ext_vector_type(8)));
typedef float    f32x4  __attribute__((ext_vector_type(4)));

__device__ __forceinline__ float fdot2(half2_t a, half2_t b, float c) {
  return __builtin_amdgcn_fdot2(a, b, c, false);
}

// LDS slot index for (d-group g, pixel p): one 16B pad slot every 8 pixels.
// Old layout had p-stride 16B -> quad term (p += 8) = 128B = bank-period ->
// systematic 4-way conflict on every phase-3 read (the constant 2.94M
// SQ_LDS_BANK_CONFLICT). New stride for p+=8 is 144B = +4 banks -> quads
// land on disjoint bank groups; all three access patterns are <=2-way (free).
#define SLOT(g, p) ((g) * 72 + (p) + ((p) >> 3))

// Workgroup barrier that drains only LDS (lgkmcnt), never vmcnt.
// In-flight VMEM across barriers is only thread-private xv prefetch loads;
// the compiler inserts counted vmcnt(N) waits at each consumption point.
#define BAR() asm volatile("s_waitcnt lgkmcnt(0)\n\ts_barrier" ::: "memory")

// ws layout (float offsets)
#define OFF_ASUM   0
#define OFF_APART  (NB * NK)
#define OFF_EPART  (OFF_APART + GRID * NK)
#define WS_NEED    ((size_t)OFF_EPART * 4 + (size_t)GRID * NK * NDIM * 2)

// ---- fused MFMA kernel ----
// R11: revert R4's spin-fusion (regression). R3 skeleton + bank-conflict-free
// XbS layout (SLOT) + single buffer at 49.1KB LDS -> 3 blocks/CU (12 waves),
// grid 768 single-pass. launch_bounds(256,3) caps VGPR at 128 so all 3
// LDS-resident blocks also fit register-wise.
__global__ __launch_bounds__(256, 3) void encode_main(
    const float* __restrict__ X, const float* __restrict__ Cw,
    const float* __restrict__ scale,
    void* __restrict__ Eout, float* __restrict__ Aout, int mode)
{
  __shared__ _Float16 XbS[32 * 72 * 8];   // SLOT layout, 36,864 B
  __shared__ _Float16 Al[NK][72];         // softmax weights [k][p], 9,216 B
  __shared__ float red2[4][TN];
  __shared__ float redM[4][TN];
  __shared__ float redS[4][TN];
  // total LDS: 36864 + 9216 + 3*1024 = 49,152 B -> 3 blocks/CU (147,456)

  const int tid  = threadIdx.x;
  const int w    = __builtin_amdgcn_readfirstlane(tid >> 6);
  const int lane = tid & 63;
  const int m    = lane & 15, quad = lane >> 4;
  const int b    = blockIdx.x / NW;
  const int wid  = blockIdx.x % NW;
  const int pix0 = wid * (TPB * TN);       // contiguous 3-tile strip
  const float* Xbase = X + (size_t)b * NDIM * NPIX;
  const int kbase = w * 16;

  float xv[64];
  // ---- issue tile-0 X loads first; prologue below hides under them ----
  {
    const float* Xg = Xbase + (size_t)(w * 64) * NPIX + pix0 + lane;
#pragma unroll
    for (int i = 0; i < 64; ++i) xv[i] = Xg[(size_t)i * NPIX];
  }

  // ---- per-block c2[k] partials (redM reused as scratch pre-loop) ----
  {
    const int kk = tid >> 2, ch = tid & 3;
    const float* Cr = Cw + kk * NDIM + ch * 64;
    float s = 0.f;
#pragma unroll
    for (int j = 0; j < 16; ++j) {
      const float4 v = *(const float4*)(Cr + 4 * j);
      s += v.x * v.x + v.y * v.y + v.z * v.z + v.w * v.w;
    }
    redM[ch][kk] = s;
  }

  // ---- phase-1 A-frags from Cw, converted in small chunks (8 src regs
  //      live at a time) so af1 build never co-peaks with xv[64] ----
  half8_t af1[8];
#pragma unroll
  for (int ks = 0; ks < 8; ++ks) {
    const float* ap = Cw + (kbase + m) * NDIM + ks * 32 + quad * 8;
    const float4 a0 = *(const float4*)(ap);
    const float4 a1 = *(const float4*)(ap + 4);
    half8_t h;
    h[0] = (_Float16)a0.x; h[1] = (_Float16)a0.y;
    h[2] = (_Float16)a0.z; h[3] = (_Float16)a0.w;
    h[4] = (_Float16)a1.x; h[5] = (_Float16)a1.y;
    h[6] = (_Float16)a1.z; h[7] = (_Float16)a1.w;
    af1[ks] = h;
    __builtin_amdgcn_sched_barrier(0);   // pin: keep Cw loads chunked
  }

  const float4 scv = *(const float4*)(scale + kbase + quad * 4);
  const float sc[4] = {scv.x, scv.y, scv.z, scv.w};

  BAR();                               // c2 partials visible
  float sq[4];
#pragma unroll
  for (int r = 0; r < 4; ++r) {
    const int k = kbase + quad * 4 + r;
    const float c2k = redM[0][k] + redM[1][k] + redM[2][k] + redM[3][k];
    sq[r] = sc[r] * c2k;
  }

  f32x4 acc_e[4][4];
#pragma unroll
  for (int i = 0; i < 4; ++i)
#pragma unroll
    for (int j = 0; j < 4; ++j)
      acc_e[i][j] = (f32x4){0.f, 0.f, 0.f, 0.f};
  float asum_acc = 0.f;

  for (int tt = 0; tt < TPB; ++tt) {
    BAR();                             // B1: prev tile's phase-3 reads done

    // ---- stage from prefetch regs: cvt f16 + xsq, LDS b128 writes ----
    {
      float xsq = 0.f;
#pragma unroll
      for (int g = 0; g < 8; ++g) {
        half8_t hv;
#pragma unroll
        for (int i = 0; i < 8; ++i) {
          const float v = xv[g * 8 + i];
          hv[i] = (_Float16)v; xsq += v * v;
        }
        *(half8_t*)&XbS[SLOT(w * 8 + g, lane) * 8] = hv;
      }
      red2[w][lane] = xsq;
    }
    BAR();                             // B2: XbS + red2 visible

    // ---- issue next tile's loads NOW; consumed after next B1 (one full
    //      tile of compute ahead; lgkm-only barriers keep them in flight) ----
    if (tt + 1 < TPB) {
      const float* Xg = Xbase + (size_t)(w * 64) * NPIX + pix0 + (tt + 1) * TN + lane;
#pragma unroll
      for (int i = 0; i < 64; ++i) xv[i] = Xg[(size_t)i * NPIX];
    }

    // ---- phase 1 MFMA: S^T[k 16][p 64] per wave ----
    f32x4 accs[4];
#pragma unroll
    for (int nt = 0; nt < 4; ++nt) accs[nt] = (f32x4){0.f, 0.f, 0.f, 0.f};
    __builtin_amdgcn_s_setprio(1);
#pragma unroll
    for (int ks = 0; ks < 8; ++ks) {
#pragma unroll
      for (int nt = 0; nt < 4; ++nt) {
        const half8_t bf = *(const half8_t*)&XbS[SLOT(ks * 4 + quad, nt * 16 + m) * 8];
        accs[nt] = __builtin_amdgcn_mfma_f32_16x16x32_f16(af1[ks], bf, accs[nt], 0, 0, 0);
      }
    }
    __builtin_amdgcn_s_setprio(0);

    // ---- phase 2: softmax; in-wave shfl + one LDS exchange ----
    float e[4][4], mw[4];
#pragma unroll
    for (int nt = 0; nt < 4; ++nt) {
      const int p = nt * 16 + m;
      const float x2p = red2[0][p] + red2[1][p] + red2[2][p] + red2[3][p];
      float L[4];
      float mx = -3.0e38f;
#pragma unroll
      for (int r = 0; r < 4; ++r) {
        L[r] = sc[r] * x2p - 2.f * sc[r] * accs[nt][r] + sq[r];
        mx = fmaxf(mx, L[r]);
      }
      mx = fmaxf(mx, __shfl_xor(mx, 16));
      mx = fmaxf(mx, __shfl_xor(mx, 32));
      float s = 0.f;
#pragma unroll
      for (int r = 0; r < 4; ++r) { e[nt][r] = __expf(L[r] - mx); s += e[nt][r]; }
      s += __shfl_xor(s, 16);
      s += __shfl_xor(s, 32);
      mw[nt] = mx;
      if (lane < 16) { redM[w][p] = mx; redS[w][p] = s; }
    }
    BAR();                             // B3: cross-wave max/sum exchange
#pragma unroll
    for (int nt = 0; nt < 4; ++nt) {
      const int p = nt * 16 + m;
      const float M = fmaxf(fmaxf(redM[0][p], redM[1][p]),
                            fmaxf(redM[2][p], redM[3][p]));
      const float T = redS[0][p] * __expf(redM[0][p] - M)
                    + redS[1][p] * __expf(redM[1][p] - M)
                    + redS[2][p] * __expf(redM[2][p] - M)
                    + redS[3][p] * __expf(redM[3][p] - M);
      const float norm = __expf(mw[nt] - M) / T;
#pragma unroll
      for (int r = 0; r < 4; ++r)
        Al[kbase + quad * 4 + r][p] = (_Float16)(e[nt][r] * norm);
    }
    BAR();                             // B4: Al visible

    // ---- phase 3 MFMA: E^T[d 64][k 64] per wave ----
    __builtin_amdgcn_s_setprio(1);
#pragma unroll
    for (int ks = 0; ks < 2; ++ks) {
      half8_t ba[4];
#pragma unroll
      for (int kt = 0; kt < 4; ++kt)
        ba[kt] = *(const half8_t*)&Al[kt * 16 + m][ks * 32 + quad * 8];
#pragma unroll
      for (int dt = 0; dt < 4; ++dt) {
        const int c = w * 8 + dt * 2 + (m >> 3);
        const int dlow = m & 7;
        half8_t xa;
#pragma unroll
        for (int j = 0; j < 8; ++j)
          xa[j] = XbS[SLOT(c, ks * 32 + quad * 8 + j) * 8 + dlow];
#pragma unroll
        for (int kt = 0; kt < 4; ++kt)
          acc_e[dt][kt] = __builtin_amdgcn_mfma_f32_16x16x32_f16(xa, ba[kt], acc_e[dt][kt], 0, 0, 0);
      }
    }
    __builtin_amdgcn_s_setprio(0);

    // ---- asum rows: balanced over all 4 waves (16 k each), 4-lane reduce ----
    {
      const half2_t one = {(_Float16)1.f, (_Float16)1.f};
      const int ka = kbase + (lane >> 2);
      const int pa = (lane & 3) * 16;
      float s = 0.f;
#pragma unroll
      for (int lc = 0; lc < 2; ++lc) {
        const half8_t sv = *(const half8_t*)&Al[ka][pa + lc * 8];
        s = fdot2(__builtin_shufflevector(sv, sv, 0, 1), one, s);
        s = fdot2(__builtin_shufflevector(sv, sv, 2, 3), one, s);
        s = fdot2(__builtin_shufflevector(sv, sv, 4, 5), one, s);
        s = fdot2(__builtin_shufflevector(sv, sv, 6, 7), one, s);
      }
      s += __shfl_xor(s, 1);
      s += __shfl_xor(s, 2);
      asum_acc += s;                   // valid on lanes with (lane&3)==0
    }
  }

  // ---- epilogue: transpose frags through LDS (XbS dead -> alias as Et) ----
  BAR();
  _Float16* Et = XbS;                  // [64][264] = 33,792 B <= 36,864 B
#pragma unroll
  for (int dt = 0; dt < 4; ++dt)
#pragma unroll
    for (int kt = 0; kt < 4; ++kt)
#pragma unroll
      for (int r = 0; r < 4; ++r) {
        const int k = kt * 16 + m;               // C/D: col=lane&15 -> k
        const int d = w * 64 + dt * 16 + quad * 4 + r;
        Et[k * 264 + d] = (_Float16)acc_e[dt][kt][r];
      }
  BAR();
  const int ko = tid >> 2, cq = tid & 3;
  if (mode) {
    _Float16* Ebk = (_Float16*)Eout + (size_t)blockIdx.x * (NK * NDIM);
#pragma unroll
    for (int g = 0; g < 8; ++g)
      *(half8_t*)&Ebk[ko * NDIM + cq * 64 + g * 8] =
          *(const half8_t*)&Et[ko * 264 + cq * 64 + g * 8];
    if ((lane & 3) == 0)
      Aout[blockIdx.x * NK + kbase + (lane >> 2)] = asum_acc;
  } else {
    float* Ebk = (float*)Eout + (size_t)b * (NK * NDIM);
#pragma unroll
    for (int g = 0; g < 64; ++g)
      atomicAdd(&Ebk[ko * NDIM + cq * 64 + g], (float)Et[ko * 264 + cq * 64 + g]);
    if ((lane & 3) == 0)
      atomicAdd(&Aout[b * NK + kbase + (lane >> 2)], asum_acc);
  }
}

// ---- out = sum_w Epart(f16) - asum*C ; asum fused; 256-block wide ----
__global__ void finalize_partials(const _Float16* __restrict__ EpartH,
                                  const float* __restrict__ Apart,
                                  const float* __restrict__ Cw,
                                  float* __restrict__ out) {
  const int g = blockIdx.x * 256 + threadIdx.x;  // half4-group id, 0..65535
  const int i0 = g * 4;
  const int bb = i0 >> 14;
  const int o  = i0 & 16383;           // k*256+d within batch
  const int k  = o >> 8, d = i0 & 255;
  // asum[bb][k]: 48 scalar loads, identical across the 64 threads sharing
  // (bb,k) in a wave -> broadcast from L1; replaces a dedicated launch.
  float a = 0.f;
#pragma unroll 8
  for (int w = 0; w < NW; ++w) a += Apart[(bb * NW + w) * NK + k];
  float s0 = 0.f, s1 = 0.f, s2 = 0.f, s3 = 0.f;
  const _Float16* base = EpartH + (((size_t)bb * NW) << 14) + o;
#pragma unroll 4
  for (int w = 0; w < NW; ++w) {
    const half4_t v = *(const half4_t*)(base + ((size_t)w << 14));
    s0 += (float)v[0]; s1 += (float)v[1];
    s2 += (float)v[2]; s3 += (float)v[3];
  }
  const float4 c0 = *(const float4*)(Cw + k * NDIM + d);
  float4 r0;
  r0.x = s0 - a * c0.x; r0.y = s1 - a * c0.y;
  r0.z = s2 - a * c0.z; r0.w = s3 - a * c0.w;
  *(float4*)(out + i0) = r0;
}

// ---- out = E_acc - asum*C (atomic-fallback mode) ----
__global__ void finalize_atomic(const float* __restrict__ E_acc,
                                const float* __restrict__ asum,
                                const float* __restrict__ Cw,
                                float* __restrict__ out) {
  const int i = blockIdx.x * 256 + threadIdx.x;
  const int d = i & 255;
  const int k = (i >> 8) & 63;
  const int bb = i >> 14;
  out[i] = E_acc[i] - asum[bb * NK + k] * Cw[k * NDIM + d];
}

extern "C" void kernel_launch(void* const* d_in, const int* in_sizes, int n_in,
                              void* d_out, int out_size, void* d_ws, size_t ws_size,
                              hipStream_t stream) {
  const float* X     = (const float*)d_in[0];
  const float* Cw    = (const float*)d_in[1];
  const float* scale = (const float*)d_in[2];
  float* out = (float*)d_out;

  float* wsf = (float*)d_ws;
  float* asum  = wsf + OFF_ASUM;
  float* Apart = wsf + OFF_APART;

  if (ws_size >= WS_NEED) {
    _Float16* EpartH = (_Float16*)(wsf + OFF_EPART);
    encode_main<<<GRID, 256, 0, stream>>>(X, Cw, scale, EpartH, Apart, 1);
    finalize_partials<<<(NB*NK*NDIM)/(256*4), 256, 0, stream>>>(EpartH, Apart, Cw, out);
  } else {
    float* E_acc = wsf + OFF_APART;   // fallback: fp32 atomic accumulator
    hipMemsetAsync(wsf, 0,
                   (size_t)(NB*NK + NB*NK*NDIM) * sizeof(float), stream);
    encode_main<<<GRID, 256, 0, stream>>>(X, Cw, scale, E_acc, asum, 0);
    finalize_atomic<<<(NB*NK*NDIM)/256, 256, 0, stream>>>(E_acc, asum, Cw, out);
  }
}

// Round 6
// 236.466 us; speedup vs baseline: 1.5608x; 1.5608x over previous
//
#include <hip/hip_runtime.h>

// Problem constants (fixed by the reference: B=16, D=256, K=64, H=W=96)
#define NDIM  256
#define NK    64
#define NPIX  9216
#define NB    16
#define TN    64           // pixels per tile
#define NW    32           // writer blocks per batch (single-pass: 512 blocks)
#define GRID  (NB*NW)      // 512 = exactly 2 blocks/CU resident -> one pass

typedef _Float16 half2_t __attribute__((ext_vector_type(2)));
typedef _Float16 half4_t __attribute__((ext_vector_type(4)));
typedef _Float16 half8_t __attribute__((ext_vector_type(8)));
typedef float    f32x4  __attribute__((ext_vector_type(4)));

__device__ __forceinline__ float fdot2(half2_t a, half2_t b, float c) {
  return __builtin_amdgcn_fdot2(a, b, c, false);
}

// Workgroup barrier that drains only LDS (lgkmcnt), never vmcnt.
// In-flight VMEM across barriers is only thread-private xv prefetch loads;
// the compiler inserts counted vmcnt(N) waits at each consumption point.
#define BAR() asm volatile("s_waitcnt lgkmcnt(0)\n\ts_barrier" ::: "memory")

// ws layout (float offsets)
#define OFF_ASUM   0
#define OFF_APART  (NB * NK)
#define OFF_EPART  (OFF_APART + GRID * NK)
#define WS_NEED    ((size_t)OFF_EPART * 4 + (size_t)GRID * NK * NDIM * 2)

// ---- fused MFMA kernel ----
// R12 = R3's proven skeleton (239.3us) + ONE change: blockIdx decomposition
// swapped to (b = idx & 15, wid = idx >> 4). X's d-stride (36,864B) is
// 0 mod 4KB, so a tile-column's 256B chunks all alias one L2/HBM channel
// class; under the old mapping, same-XCD blocks (idx = r mod 8) also had
// wid = r mod 8, concentrating each XCD's traffic on ~2/16 channel
// residues. New mapping gives same-XCD blocks CONSECUTIVE wid -> pix0
// walks 5*wid mod 16 (coprime) -> all channel classes covered per XCD.
// NOTE: __launch_bounds__(256,N) empirically caps arch VGPRs at ~256/N
// (R2/R4: 128, R5: 84 -> xv[64] spilled catastrophically). Keep (256,2).
__global__ __launch_bounds__(256, 2) void encode_main(
    const float* __restrict__ X, const float* __restrict__ Cw,
    const float* __restrict__ scale,
    void* __restrict__ Eout, float* __restrict__ Aout, int mode)
{
  __shared__ _Float16 XbS[2][32 * 66 * 8];  // Xb[buf][d>>3][p][d&7], 2x33,792 B
  __shared__ _Float16 Al[NK][72];           // softmax weights [k][p]
  __shared__ float red2[4][TN];
  __shared__ float redM[4][TN];
  __shared__ float redS[4][TN];
  // total LDS: 67584 + 9216 + 3*1024 = 79872 B -> exactly 2 blocks/CU

  const int tid  = threadIdx.x;
  const int w    = __builtin_amdgcn_readfirstlane(tid >> 6);
  const int lane = tid & 63;
  const int m    = lane & 15, quad = lane >> 4;
  const int b    = blockIdx.x & 15;        // batch  (swapped: was idx/NW)
  const int wid  = blockIdx.x >> 4;        // strip  (swapped: was idx%NW)
  // 144 tiles/batch over 32 blocks: first 16 blocks take 5 tiles, rest 4.
  const int ntiles = (wid < 16) ? 5 : 4;
  const int pix0   = (wid * 4 + (wid < 16 ? wid : 16)) * TN;
  const float* Xbase = X + (size_t)b * NDIM * NPIX;
  const int kbase = w * 16;

  float xv[64];
  // ---- issue tile-0 X loads first; prologue below hides under them ----
  {
    const float* Xg = Xbase + (size_t)(w * 64) * NPIX + pix0 + lane;
#pragma unroll
    for (int i = 0; i < 64; ++i) xv[i] = Xg[(size_t)i * NPIX];
  }

  // ---- per-block c2[k] partials (redM reused as scratch pre-loop) ----
  {
    const int kk = tid >> 2, ch = tid & 3;
    const float* Cr = Cw + kk * NDIM + ch * 64;
    float s = 0.f;
#pragma unroll
    for (int j = 0; j < 16; ++j) {
      const float4 v = *(const float4*)(Cr + 4 * j);
      s += v.x * v.x + v.y * v.y + v.z * v.z + v.w * v.w;
    }
    redM[ch][kk] = s;
  }

  // ---- phase-1 A-frags from Cw, converted in small chunks (8 src regs
  //      live at a time) so af1 build never co-peaks with xv[64] ----
  half8_t af1[8];
#pragma unroll
  for (int ks = 0; ks < 8; ++ks) {
    const float* ap = Cw + (kbase + m) * NDIM + ks * 32 + quad * 8;
    const float4 a0 = *(const float4*)(ap);
    const float4 a1 = *(const float4*)(ap + 4);
    half8_t h;
    h[0] = (_Float16)a0.x; h[1] = (_Float16)a0.y;
    h[2] = (_Float16)a0.z; h[3] = (_Float16)a0.w;
    h[4] = (_Float16)a1.x; h[5] = (_Float16)a1.y;
    h[6] = (_Float16)a1.z; h[7] = (_Float16)a1.w;
    af1[ks] = h;
    __builtin_amdgcn_sched_barrier(0);   // pin: keep Cw loads chunked
  }

  const float4 scv = *(const float4*)(scale + kbase + quad * 4);
  const float sc[4] = {scv.x, scv.y, scv.z, scv.w};

  BAR();                               // c2 partials visible
  float sq[4];
#pragma unroll
  for (int r = 0; r < 4; ++r) {
    const int k = kbase + quad * 4 + r;
    const float c2k = redM[0][k] + redM[1][k] + redM[2][k] + redM[3][k];
    sq[r] = sc[r] * c2k;
  }

  f32x4 acc_e[4][4];
#pragma unroll
  for (int i = 0; i < 4; ++i)
#pragma unroll
    for (int j = 0; j < 4; ++j)
      acc_e[i][j] = (f32x4){0.f, 0.f, 0.f, 0.f};
  float asum_acc = 0.f;

  // ---- stage helpers ----
  auto STAGE = [&](int bufi) {
    _Float16* Xb = XbS[bufi];
    float xsq = 0.f;
#pragma unroll
    for (int g = 0; g < 8; ++g) {
      half8_t hv;
#pragma unroll
      for (int i = 0; i < 8; ++i) {
        const float v = xv[g * 8 + i];
        hv[i] = (_Float16)v; xsq += v * v;
      }
      *(half8_t*)&Xb[((w * 8 + g) * 66 + lane) * 8] = hv;
    }
    red2[w][lane] = xsq;
  };
  auto ISSUE = [&](int t) {
    const float* Xg = Xbase + (size_t)(w * 64) * NPIX + pix0 + t * TN + lane;
#pragma unroll
    for (int i = 0; i < 64; ++i) xv[i] = Xg[(size_t)i * NPIX];
  };

  // ---- prologue: stage tile 0, issue tile 1 ----
  STAGE(0);
  ISSUE(1);                            // ntiles >= 4 always
  BAR();                               // B_main(t0): XbS[0] + red2 visible

  for (int tt = 0; tt < ntiles; ++tt) {
    const _Float16* Xb = XbS[tt & 1];

    // ---- phase 1 MFMA: S^T[k 16][p 64] per wave ----
    f32x4 accs[4];
#pragma unroll
    for (int nt = 0; nt < 4; ++nt) accs[nt] = (f32x4){0.f, 0.f, 0.f, 0.f};
    __builtin_amdgcn_s_setprio(1);
#pragma unroll
    for (int ks = 0; ks < 8; ++ks) {
#pragma unroll
      for (int nt = 0; nt < 4; ++nt) {
        const half8_t bf = *(const half8_t*)&Xb[((ks * 4 + quad) * 66 + nt * 16 + m) * 8];
        accs[nt] = __builtin_amdgcn_mfma_f32_16x16x32_f16(af1[ks], bf, accs[nt], 0, 0, 0);
      }
    }
    __builtin_amdgcn_s_setprio(0);

    // ---- phase 2: softmax; in-wave shfl + one LDS exchange ----
    float e[4][4], mw[4];
#pragma unroll
    for (int nt = 0; nt < 4; ++nt) {
      const int p = nt * 16 + m;
      const float x2p = red2[0][p] + red2[1][p] + red2[2][p] + red2[3][p];
      float L[4];
      float mx = -3.0e38f;
#pragma unroll
      for (int r = 0; r < 4; ++r) {
        L[r] = sc[r] * x2p - 2.f * sc[r] * accs[nt][r] + sq[r];
        mx = fmaxf(mx, L[r]);
      }
      mx = fmaxf(mx, __shfl_xor(mx, 16));
      mx = fmaxf(mx, __shfl_xor(mx, 32));
      float s = 0.f;
#pragma unroll
      for (int r = 0; r < 4; ++r) { e[nt][r] = __expf(L[r] - mx); s += e[nt][r]; }
      s += __shfl_xor(s, 16);
      s += __shfl_xor(s, 32);
      mw[nt] = mx;
      if (lane < 16) { redM[w][p] = mx; redS[w][p] = s; }
    }
    BAR();                             // B_x: cross-wave max/sum exchange
#pragma unroll
    for (int nt = 0; nt < 4; ++nt) {
      const int p = nt * 16 + m;
      const float M = fmaxf(fmaxf(redM[0][p], redM[1][p]),
                            fmaxf(redM[2][p], redM[3][p]));
      const float T = redS[0][p] * __expf(redM[0][p] - M)
                    + redS[1][p] * __expf(redM[1][p] - M)
                    + redS[2][p] * __expf(redM[2][p] - M)
                    + redS[3][p] * __expf(redM[3][p] - M);
      const float norm = __expf(mw[nt] - M) / T;
#pragma unroll
      for (int r = 0; r < 4; ++r)
        Al[kbase + quad * 4 + r][p] = (_Float16)(e[nt][r] * norm);
    }
    BAR();                             // B_al: Al visible

    // ---- phase 3 MFMA: E^T[d 64][k 64] per wave ----
    __builtin_amdgcn_s_setprio(1);
#pragma unroll
    for (int ks = 0; ks < 2; ++ks) {
      half8_t ba[4];
#pragma unroll
      for (int kt = 0; kt < 4; ++kt)
        ba[kt] = *(const half8_t*)&Al[kt * 16 + m][ks * 32 + quad * 8];
#pragma unroll
      for (int dt = 0; dt < 4; ++dt) {
        const int c = w * 8 + dt * 2 + (m >> 3);
        const int dlow = m & 7;
        half8_t xa;
#pragma unroll
        for (int j = 0; j < 8; ++j)
          xa[j] = Xb[(c * 66 + ks * 32 + quad * 8 + j) * 8 + dlow];
#pragma unroll
        for (int kt = 0; kt < 4; ++kt)
          acc_e[dt][kt] = __builtin_amdgcn_mfma_f32_16x16x32_f16(xa, ba[kt], acc_e[dt][kt], 0, 0, 0);
      }
    }
    __builtin_amdgcn_s_setprio(0);

    // ---- asum rows: balanced over all 4 waves (16 k each), 4-lane reduce ----
    {
      const half2_t one = {(_Float16)1.f, (_Float16)1.f};
      const int ka = kbase + (lane >> 2);
      const int pa = (lane & 3) * 16;
      float s = 0.f;
#pragma unroll
      for (int lc = 0; lc < 2; ++lc) {
        const half8_t sv = *(const half8_t*)&Al[ka][pa + lc * 8];
        s = fdot2(__builtin_shufflevector(sv, sv, 0, 1), one, s);
        s = fdot2(__builtin_shufflevector(sv, sv, 2, 3), one, s);
        s = fdot2(__builtin_shufflevector(sv, sv, 4, 5), one, s);
        s = fdot2(__builtin_shufflevector(sv, sv, 6, 7), one, s);
      }
      s += __shfl_xor(s, 1);
      s += __shfl_xor(s, 2);
      asum_acc += s;                   // valid on lanes with (lane&3)==0
    }

    // ---- stage tile t+1 into the other buffer; issue tile t+2 loads.
    //      Loads consumed here were issued ~1.5 tiles ago. ----
    if (tt + 1 < ntiles) {
      STAGE((tt + 1) & 1);
      if (tt + 2 < ntiles) ISSUE(tt + 2);
      BAR();                           // B_main(t+1)
    }
  }

  // ---- epilogue: transpose frags through LDS (XbS dead -> alias as Et) ----
  BAR();
  _Float16* Et = XbS[0];               // [64][264]
#pragma unroll
  for (int dt = 0; dt < 4; ++dt)
#pragma unroll
    for (int kt = 0; kt < 4; ++kt)
#pragma unroll
      for (int r = 0; r < 4; ++r) {
        const int k = kt * 16 + m;               // C/D: col=lane&15 -> k
        const int d = w * 64 + dt * 16 + quad * 4 + r;
        Et[k * 264 + d] = (_Float16)acc_e[dt][kt][r];
      }
  BAR();
  const int ko = tid >> 2, cq = tid & 3;
  if (mode) {
    _Float16* Ebk = (_Float16*)Eout + (size_t)blockIdx.x * (NK * NDIM);
#pragma unroll
    for (int g = 0; g < 8; ++g)
      *(half8_t*)&Ebk[ko * NDIM + cq * 64 + g * 8] =
          *(const half8_t*)&Et[ko * 264 + cq * 64 + g * 8];
    if ((lane & 3) == 0)
      Aout[blockIdx.x * NK + kbase + (lane >> 2)] = asum_acc;
  } else {
    float* Ebk = (float*)Eout + (size_t)b * (NK * NDIM);
#pragma unroll
    for (int g = 0; g < 64; ++g)
      atomicAdd(&Ebk[ko * NDIM + cq * 64 + g], (float)Et[ko * 264 + cq * 64 + g]);
    if ((lane & 3) == 0)
      atomicAdd(&Aout[b * NK + kbase + (lane >> 2)], asum_acc);
  }
}

// ---- out = sum_w Epart(f16) - asum*C ; asum fused; 256-block wide ----
// Slab index for (batch bb, strip w2) is now w2*NB + bb (swapped mapping).
__global__ void finalize_partials(const _Float16* __restrict__ EpartH,
                                  const float* __restrict__ Apart,
                                  const float* __restrict__ Cw,
                                  float* __restrict__ out) {
  const int g = blockIdx.x * 256 + threadIdx.x;  // half4-group id, 0..65535
  const int i0 = g * 4;
  const int bb = i0 >> 14;
  const int o  = i0 & 16383;           // k*256+d within batch
  const int k  = o >> 8, d = i0 & 255;
  float a = 0.f;
#pragma unroll 8
  for (int w = 0; w < NW; ++w) a += Apart[(w * NB + bb) * NK + k];
  float s0 = 0.f, s1 = 0.f, s2 = 0.f, s3 = 0.f;
  const _Float16* base = EpartH + o;
#pragma unroll 4
  for (int w = 0; w < NW; ++w) {
    const half4_t v = *(const half4_t*)(base + (((size_t)(w * NB + bb)) << 14));
    s0 += (float)v[0]; s1 += (float)v[1];
    s2 += (float)v[2]; s3 += (float)v[3];
  }
  const float4 c0 = *(const float4*)(Cw + k * NDIM + d);
  float4 r0;
  r0.x = s0 - a * c0.x; r0.y = s1 - a * c0.y;
  r0.z = s2 - a * c0.z; r0.w = s3 - a * c0.w;
  *(float4*)(out + i0) = r0;
}

// ---- out = E_acc - asum*C (atomic-fallback mode) ----
__global__ void finalize_atomic(const float* __restrict__ E_acc,
                                const float* __restrict__ asum,
                                const float* __restrict__ Cw,
                                float* __restrict__ out) {
  const int i = blockIdx.x * 256 + threadIdx.x;
  const int d = i & 255;
  const int k = (i >> 8) & 63;
  const int bb = i >> 14;
  out[i] = E_acc[i] - asum[bb * NK + k] * Cw[k * NDIM + d];
}

extern "C" void kernel_launch(void* const* d_in, const int* in_sizes, int n_in,
                              void* d_out, int out_size, void* d_ws, size_t ws_size,
                              hipStream_t stream) {
  const float* X     = (const float*)d_in[0];
  const float* Cw    = (const float*)d_in[1];
  const float* scale = (const float*)d_in[2];
  float* out = (float*)d_out;

  float* wsf = (float*)d_ws;
  float* asum  = wsf + OFF_ASUM;
  float* Apart = wsf + OFF_APART;

  if (ws_size >= WS_NEED) {
    _Float16* EpartH = (_Float16*)(wsf + OFF_EPART);
    encode_main<<<GRID, 256, 0, stream>>>(X, Cw, scale, EpartH, Apart, 1);
    finalize_partials<<<(NB*NK*NDIM)/(256*4), 256, 0, stream>>>(EpartH, Apart, Cw, out);
  } else {
    float* E_acc = wsf + OFF_APART;   // fallback: fp32 atomic accumulator
    hipMemsetAsync(wsf, 0,
                   (size_t)(NB*NK + NB*NK*NDIM) * sizeof(float), stream);
    encode_main<<<GRID, 256, 0, stream>>>(X, Cw, scale, E_acc, asum, 0);
    finalize_atomic<<<(NB*NK*NDIM)/256, 256, 0, stream>>>(E_acc, asum, Cw, out);
  }
}